// Round 12
// baseline (106.144 us; speedup 1.0000x reference)
//
#include <hip/hip_runtime.h>
#include <hip/hip_bf16.h>
#include <math.h>
#include <string.h>

#define NB 2
#define NN 2304        // 48*48
#define NHEADS 8
#define DH 32
#define AW 8           // waves per attn block
#define KPW 288        // keys per wave (NN/8)

typedef __attribute__((ext_vector_type(8))) short v8s;   // 8 bf16 in 4 VGPRs
typedef __attribute__((ext_vector_type(4))) float v4f;

__device__ inline unsigned short f2b(float f) {          // fp32 -> bf16 (RNE)
    unsigned u = __builtin_bit_cast(unsigned, f);
    unsigned r = u + 0x7FFFu + ((u >> 16) & 1u);
    return (unsigned short)(r >> 16);
}
__device__ inline float b2f(short s) {
    unsigned u = ((unsigned)(unsigned short)s) << 16;
    return __builtin_bit_cast(float, u);
}
__device__ inline unsigned pk2(float a, float b) {       // 2 fp32 -> packed bf16x2
    __hip_bfloat162 h = __float22bfloat162_rn(make_float2(a, b));
    unsigned r;
    memcpy(&r, &h, sizeof(r));
    return r;
}
__device__ inline float blo(unsigned u) { return __builtin_bit_cast(float, u << 16); }
__device__ inline float bhi(unsigned u) { return __builtin_bit_cast(float, u & 0xffff0000u); }

// ---------------- fused front: x transpose | invL | conv1 | weight prep ----------------
__global__ void k_front(const float* __restrict__ x, short* __restrict__ xt,
                        const float* __restrict__ luma, float* __restrict__ invl,
                        const float* __restrict__ wc1, const float* __restrict__ bc1,
                        short* __restrict__ h1p,
                        const float* __restrict__ wc2, const float* __restrict__ wqkv,
                        const float* __restrict__ wg, const float* __restrict__ wbt,
                        const float* __restrict__ wproj,
                        short* __restrict__ tc2b, short* __restrict__ wqkvb,
                        short* __restrict__ wgb, short* __restrict__ wbtb,
                        short* __restrict__ wprojb, float* __restrict__ vsum) {
    __shared__ unsigned short lds[64 * 66];
    __shared__ float red[256];
    int blk = blockIdx.x;
    const int XT_END = NB * 144;
    const int INVL_END = XT_END + NB;
    const int CONV1_END = INVL_END + NB * 1250;
    if (blk >= CONV1_END) {
        int i = (blk - CONV1_END) * 256 + threadIdx.x;
        if (i < 16 * DH) vsum[i] = 0.f;
        if (i < 9 * 128 * 128) {                       // tc2b[s][o][ic] = wc2[o][ic][s]
            int s = i / (128 * 128);
            int rem = i % (128 * 128);
            int o = rem / 128, ic = rem % 128;
            tc2b[i] = (short)f2b(wc2[(o * 128 + ic) * 9 + s]);
        }
        if (i < 768 * 256) wqkvb[i] = (short)f2b(wqkv[i]);
        if (i < 256 * 128) { wgb[i] = (short)f2b(wg[i]); wbtb[i] = (short)f2b(wbt[i]); }
        if (i < 256 * 256) wprojb[i] = (short)f2b(wproj[i]);
        return;
    }
    if (blk >= INVL_END) {
        // ---- conv1 -> h1p padded(50x50) transposed [b][p][128] bf16 ----
        int cb = blk - INVL_END;
        int c = threadIdx.x & 127;
        int p = (cb % 1250) * 2 + (threadIdx.x >> 7);
        int b = cb / 1250;
        int py = p / 50, px = p % 50;
        float val = 0.f;
        if (py >= 1 && py <= 48 && px >= 1 && px <= 48) {
            int y = py - 1, xx0 = px - 1;
            const float* lb = luma + b * NN;
            float acc = bc1[c];
#pragma unroll
            for (int ky = 0; ky < 3; ++ky) {
                int yy = y + ky - 1;
                if (yy < 0 || yy >= 48) continue;
#pragma unroll
                for (int kx = 0; kx < 3; ++kx) {
                    int xx = xx0 + kx - 1;
                    if (xx < 0 || xx >= 48) continue;
                    acc += wc1[c * 9 + ky * 3 + kx] * lb[yy * 48 + xx];
                }
            }
            val = fmaxf(acc, 0.f);
        }
        h1p[((size_t)b * 2500 + p) * 128 + c] = (short)f2b(val);
        return;
    }
    if (blk >= XT_END) {
        // ---- invL: avgpool3x3(1-luma) centered per batch ----
        int b = blk - XT_END;
        const float* lb = luma + b * NN;
        float pooled[9];
        float local = 0.f;
#pragma unroll
        for (int it = 0; it < 9; ++it) {
            int n = it * 256 + threadIdx.x;
            int y = n / 48, xx0 = n % 48;
            float s = 0.f;
            for (int ky = 0; ky < 3; ++ky) {
                int yy = y + ky - 1;
                if (yy < 0 || yy >= 48) continue;
                for (int kx = 0; kx < 3; ++kx) {
                    int xx = xx0 + kx - 1;
                    if (xx < 0 || xx >= 48) continue;
                    s += 1.f - lb[yy * 48 + xx];
                }
            }
            s *= (1.f / 9.f);
            pooled[it] = s;
            local += s;
        }
        red[threadIdx.x] = local;
        __syncthreads();
        for (int off = 128; off > 0; off >>= 1) {
            if (threadIdx.x < off) red[threadIdx.x] += red[threadIdx.x + off];
            __syncthreads();
        }
        float mean = red[0] * (1.f / NN);
#pragma unroll
        for (int it = 0; it < 9; ++it) {
            int n = it * 256 + threadIdx.x;
            invl[b * NN + n] = pooled[it] - mean;
        }
        return;
    }
    // ---- x transpose: [b][256][2304] fp32 -> xt [b][2304][256] bf16 ----
    int nt = blk % 36, ct = (blk / 36) % 4, b = blk / 144;
    int n0 = nt * 64, c0 = ct * 64;
    int nc = threadIdx.x & 63, cr = threadIdx.x >> 6;
#pragma unroll
    for (int i = 0; i < 16; ++i) {
        int cs = i * 4 + cr;
        float v = x[((size_t)b * 256 + c0 + cs) * NN + n0 + nc];
        lds[nc * 66 + cs] = f2b(v);
    }
    __syncthreads();
    int cc = threadIdx.x & 31, nr = threadIdx.x >> 5;
    unsigned* xt2 = (unsigned*)xt;
#pragma unroll
    for (int j = 0; j < 8; ++j) {
        int ns = j * 8 + nr;
        unsigned w = *(unsigned*)&lds[ns * 66 + 2 * cc];
        xt2[(((size_t)b * NN + n0 + ns) * 256 + c0) / 2 + cc] = w;
    }
}

// ---------------- fused conv2 + gamma/beta: per-block 16-n tile, h2 stays in LDS ----------------
// grid: NB * 144 (nt tile = 16 row-aligned n), block 256 (4 waves).
// Phase 1: conv2 9-shift MFMA GEMM -> h2 LDS tile [16n][128c] bf16 (bias+relu).
// Phase 2: gamma/beta GEMMs from LDS -> gtb/bttb bf16 [b][n][256].
__global__ __launch_bounds__(256) void k_cgb(const short* __restrict__ h1p,
                                             const short* __restrict__ tc2b,
                                             const float* __restrict__ bc2,
                                             const short* __restrict__ wgb,
                                             const short* __restrict__ wbtb,
                                             const float* __restrict__ bg,
                                             const float* __restrict__ bbt,
                                             short* __restrict__ gtb,
                                             short* __restrict__ bttb) {
    __shared__ unsigned short h2l[16][136];   // 272B rows (16B-aligned), 2-way bank alias
    int tid = threadIdx.x;
    int w = tid >> 6, lane = tid & 63;
    int l15 = lane & 15, g = lane >> 4;
    int blk = blockIdx.x;
    int nt = blk % 144, b = blk / 144;
    int y = nt / 3, x0 = (nt % 3) * 16;
    int n0 = y * 48 + x0;
    int p0 = (y + 1) * 50 + x0 + 1;
    const short* hb = h1p + (size_t)b * 2500 * 128;

    // ---- phase 1: conv2, wave w computes ot = 2w, 2w+1 ----
    v4f acc0 = {0.f,0.f,0.f,0.f}, acc1 = acc0;
#pragma unroll
    for (int s = 0; s < 9; ++s) {
        int dp = (s / 3 - 1) * 50 + (s % 3 - 1);
#pragma unroll
        for (int kk = 0; kk < 4; ++kk) {
            v8s B = *(const v8s*)(hb + (size_t)(p0 + dp + l15) * 128 + kk * 32 + 8 * g);
            v8s A0 = *(const v8s*)(tc2b + ((size_t)(s * 128 + (2 * w) * 16 + l15)) * 128 + kk * 32 + 8 * g);
            v8s A1 = *(const v8s*)(tc2b + ((size_t)(s * 128 + (2 * w + 1) * 16 + l15)) * 128 + kk * 32 + 8 * g);
            acc0 = __builtin_amdgcn_mfma_f32_16x16x32_bf16(A0, B, acc0, 0, 0, 0);
            acc1 = __builtin_amdgcn_mfma_f32_16x16x32_bf16(A1, B, acc1, 0, 0, 0);
        }
    }
    {
        v4f bias0 = *(const v4f*)&bc2[(2 * w) * 16 + 4 * g];
        v4f bias1 = *(const v4f*)&bc2[(2 * w + 1) * 16 + 4 * g];
        uint2 wv;
        wv.x = pk2(fmaxf(acc0[0] + bias0[0], 0.f), fmaxf(acc0[1] + bias0[1], 0.f));
        wv.y = pk2(fmaxf(acc0[2] + bias0[2], 0.f), fmaxf(acc0[3] + bias0[3], 0.f));
        *(uint2*)&h2l[l15][(2 * w) * 16 + 4 * g] = wv;
        wv.x = pk2(fmaxf(acc1[0] + bias1[0], 0.f), fmaxf(acc1[1] + bias1[1], 0.f));
        wv.y = pk2(fmaxf(acc1[2] + bias1[2], 0.f), fmaxf(acc1[3] + bias1[3], 0.f));
        *(uint2*)&h2l[l15][(2 * w + 1) * 16 + 4 * g] = wv;
    }
    __syncthreads();

    // ---- phase 2: gamma/beta, wave w handles ot = w, w+4, w+8, w+12 ----
#pragma unroll
    for (int idx = 0; idx < 4; ++idx) {
        int ot = w + idx * 4;
        v4f ga = {0.f,0.f,0.f,0.f}, ta = ga;
#pragma unroll
        for (int kk = 0; kk < 4; ++kk) {
            v8s B = *(const v8s*)&h2l[l15][kk * 32 + 8 * g];
            v8s Ag = *(const v8s*)(wgb + (size_t)(ot * 16 + l15) * 128 + kk * 32 + 8 * g);
            v8s At = *(const v8s*)(wbtb + (size_t)(ot * 16 + l15) * 128 + kk * 32 + 8 * g);
            ga = __builtin_amdgcn_mfma_f32_16x16x32_bf16(Ag, B, ga, 0, 0, 0);
            ta = __builtin_amdgcn_mfma_f32_16x16x32_bf16(At, B, ta, 0, 0, 0);
        }
        v4f bgv = *(const v4f*)&bg[ot * 16 + 4 * g];
        v4f bbv = *(const v4f*)&bbt[ot * 16 + 4 * g];
        size_t o = ((size_t)b * NN + n0 + l15) * 256 + ot * 16 + 4 * g;
        uint2 wv;
        wv.x = pk2(ga[0] + bgv[0], ga[1] + bgv[1]);
        wv.y = pk2(ga[2] + bgv[2], ga[3] + bgv[3]);
        *(uint2*)&gtb[o] = wv;
        wv.x = pk2(ta[0] + bbv[0], ta[1] + bbv[1]);
        wv.y = pk2(ta[2] + bbv[2], ta[3] + bbv[3]);
        *(uint2*)&bttb[o] = wv;
    }
}

// ---------------- qkv MFMA GEMM, 32oc x 64n/block + modulation + fused V transpose ----------------
// which==2 (V) blocks cover one head's full d=0..31 x 64 n -> write blocked vtb directly + vsum.
__global__ __launch_bounds__(64) void k_qkvm(const short* __restrict__ xt,
                                             const short* __restrict__ wqkvb,
                                             const float* __restrict__ bqkv,
                                             const short* __restrict__ gtb,
                                             const short* __restrict__ bttb,
                                             const float* __restrict__ invl,
                                             const float* __restrict__ alpha_p,
                                             short* __restrict__ qb, short* __restrict__ kb,
                                             short* __restrict__ vtb, float* __restrict__ vsum) {
    __shared__ unsigned short vlds[64][36];   // V tile [n_local][d], 72B rows
    int lane = threadIdx.x, l15 = lane & 15, g = lane >> 4;
    int blk = blockIdx.x;
    int ntg = blk % 36, otg = (blk / 36) % 24, b = blk / (36 * 24);
    int n0 = ntg * 64;
    const short* xb = xt + (size_t)b * NN * 256;

    v4f acc[2][4];
#pragma unroll
    for (int oa = 0; oa < 2; ++oa)
#pragma unroll
        for (int j = 0; j < 4; ++j) acc[oa][j] = (v4f){0.f, 0.f, 0.f, 0.f};
#pragma unroll
    for (int kk = 0; kk < 8; ++kk) {
        v8s A0 = *(const v8s*)(wqkvb + (size_t)(otg * 32 + l15) * 256 + kk * 32 + 8 * g);
        v8s A1 = *(const v8s*)(wqkvb + (size_t)(otg * 32 + 16 + l15) * 256 + kk * 32 + 8 * g);
#pragma unroll
        for (int j = 0; j < 4; ++j) {
            v8s B = *(const v8s*)(xb + (size_t)(n0 + j * 16 + l15) * 256 + kk * 32 + 8 * g);
            acc[0][j] = __builtin_amdgcn_mfma_f32_16x16x32_bf16(A0, B, acc[0][j], 0, 0, 0);
            acc[1][j] = __builtin_amdgcn_mfma_f32_16x16x32_bf16(A1, B, acc[1][j], 0, 0, 0);
        }
    }
    const float scale = 0.25503486f;     // 32^-0.5 * log2(e)
    float alpha = *alpha_p;
    int which = (otg * 32) >> 8;
#pragma unroll
    for (int oa = 0; oa < 2; ++oa) {
        int ocb = otg * 32 + oa * 16;
        int cbase = (ocb & 255) + 4 * g;
        int h = cbase >> 5, dbase = cbase & 31;
        v4f bias = *(const v4f*)&bqkv[ocb + 4 * g];
        short* dst = (which == 0) ? qb : kb;
#pragma unroll
        for (int j = 0; j < 4; ++j) {
            int n = n0 + j * 16 + l15;
            v4f a = acc[oa][j];
            uint2 gg = *(const uint2*)&gtb[((size_t)b * NN + n) * 256 + cbase];
            uint2 tt = *(const uint2*)&bttb[((size_t)b * NN + n) * 256 + cbase];
            float iv = (which == 0) ? alpha * invl[b * NN + n] : 0.f;
            float v0 = blo(gg.x) * (a[0] + bias[0]) + blo(tt.x);
            float v1 = bhi(gg.x) * (a[1] + bias[1]) + bhi(tt.x);
            float v2 = blo(gg.y) * (a[2] + bias[2]) + blo(tt.y);
            float v3 = bhi(gg.y) * (a[3] + bias[3]) + bhi(tt.y);
            if (which == 0) {
                v0 = (v0 + iv) * scale; v1 = (v1 + iv) * scale;
                v2 = (v2 + iv) * scale; v3 = (v3 + iv) * scale;
            }
            uint2 wv;
            wv.x = pk2(v0, v1);
            wv.y = pk2(v2, v3);
            if (which == 2) {
                *(uint2*)&vlds[j * 16 + l15][oa * 16 + 4 * g] = wv;   // d = oa*16+4g..+3
            } else {
                *(uint2*)&dst[(((size_t)b * NHEADS + h) * NN + n) * DH + dbase] = wv;
            }
        }
    }
    if (which == 2) {
        __syncthreads();
        int bh = b * NHEADS + (otg - 16);
        int kb0 = ntg * 2;
        // transpose: thread -> kp = lane&31 (k pair in 64 n), dh = lane>>5 (d half)
        int kp = lane & 31, dh = lane >> 5;
        unsigned* vtb2 = (unsigned*)vtb;
#pragma unroll
        for (int dd = 0; dd < 16; ++dd) {
            int d = dh * 16 + dd;
            unsigned lo = vlds[2 * kp][d];
            unsigned hi = vlds[2 * kp + 1][d];
            vtb2[(((size_t)bh * 72 + kb0 + (kp >> 4)) * 32 + d) * 16 + (kp & 15)] = lo | (hi << 16);
        }
        if (lane < 32) {
            int d = lane;
            float s = 0.f;
            for (int ns = 0; ns < 64; ++ns) s += b2f((short)vlds[ns][d]);
            atomicAdd(&vsum[bh * DH + d], s);
        }
    }
}

// ---------------- fused attention: QBLK=64/wave, 8 waves split K in-block, bf16 LDS merge ----------------
// grid 576 (XCD-swizzled), block 512.  p' = exp2(s)-1 (s pre-scaled by log2e).
__global__ __launch_bounds__(512) void k_attn2(const short* __restrict__ qb,
                                               const short* __restrict__ kbuf,
                                               const short* __restrict__ vtb,
                                               const float* __restrict__ vsum,
                                               short* __restrict__ aotb) {
    __shared__ short plds[AW][64 * 40];     // per-wave P' tile, 64 rows x 80 B
    __shared__ short acch[AW][64][36];      // per-wave partial O (bf16), 72B rows
    __shared__ float ps_lds[AW][64];        // per-wave row-sums of p'
    int tid = threadIdx.x;
    int w = tid >> 6, lane = tid & 63;
    int l15 = lane & 15, g = lane >> 4;
    int blk = blockIdx.x;
    int logical = (blk & 7) * 72 + (blk >> 3);   // XCD swizzle: 576 = 8*72
    int qt = logical % 36, bh = logical / 36;
    int qbase = qt * 64;

    const short* qp = qb + ((size_t)bh * NN + qbase) * DH;
    const short* kp = kbuf + ((size_t)bh * NN + w * KPW) * DH;
    const short* vp = vtb + ((size_t)bh * 72 + w * (KPW / 32)) * 1024;  // 32x32 tiles

    v8s q0 = *(const v8s*)(qp + l15 * DH + 8 * g);
    v8s q1 = *(const v8s*)(qp + (16 + l15) * DH + 8 * g);
    v8s q2 = *(const v8s*)(qp + (32 + l15) * DH + 8 * g);
    v8s q3 = *(const v8s*)(qp + (48 + l15) * DH + 8 * g);

    const short one_b = (short)0x3F80;      // bf16 1.0
    const v8s ones = {one_b, one_b, one_b, one_b, one_b, one_b, one_b, one_b};

    v4f acc[2][4];                          // [d-tile][q-frag]
#pragma unroll
    for (int dt = 0; dt < 2; ++dt)
#pragma unroll
        for (int qf = 0; qf < 4; ++qf) acc[dt][qf] = (v4f){0.f, 0.f, 0.f, 0.f};
    v4f ps[4] = {{0.f,0.f,0.f,0.f},{0.f,0.f,0.f,0.f},{0.f,0.f,0.f,0.f},{0.f,0.f,0.f,0.f}};
    short* pw = plds[w];

    for (int it = 0; it < KPW / 32; ++it) {
        const short* kpi = kp + it * 32 * DH;
        v8s ka0 = *(const v8s*)(kpi + l15 * DH + 8 * g);
        v8s ka1 = *(const v8s*)(kpi + (16 + l15) * DH + 8 * g);
        v4f s00 = __builtin_amdgcn_mfma_f32_16x16x32_bf16(ka0, q0, (v4f){0.f,0.f,0.f,0.f}, 0, 0, 0);
        v4f s01 = __builtin_amdgcn_mfma_f32_16x16x32_bf16(ka0, q1, (v4f){0.f,0.f,0.f,0.f}, 0, 0, 0);
        v4f s02 = __builtin_amdgcn_mfma_f32_16x16x32_bf16(ka0, q2, (v4f){0.f,0.f,0.f,0.f}, 0, 0, 0);
        v4f s03 = __builtin_amdgcn_mfma_f32_16x16x32_bf16(ka0, q3, (v4f){0.f,0.f,0.f,0.f}, 0, 0, 0);
        v4f s10 = __builtin_amdgcn_mfma_f32_16x16x32_bf16(ka1, q0, (v4f){0.f,0.f,0.f,0.f}, 0, 0, 0);
        v4f s11 = __builtin_amdgcn_mfma_f32_16x16x32_bf16(ka1, q1, (v4f){0.f,0.f,0.f,0.f}, 0, 0, 0);
        v4f s12 = __builtin_amdgcn_mfma_f32_16x16x32_bf16(ka1, q2, (v4f){0.f,0.f,0.f,0.f}, 0, 0, 0);
        v4f s13 = __builtin_amdgcn_mfma_f32_16x16x32_bf16(ka1, q3, (v4f){0.f,0.f,0.f,0.f}, 0, 0, 0);

#define DOFRAG(S, QF, KT)                                                        \
        {                                                                        \
            float p0 = __builtin_amdgcn_exp2f((S)[0]) - 1.f;                     \
            float p1 = __builtin_amdgcn_exp2f((S)[1]) - 1.f;                     \
            float p2 = __builtin_amdgcn_exp2f((S)[2]) - 1.f;                     \
            float p3 = __builtin_amdgcn_exp2f((S)[3]) - 1.f;                     \
            uint2 wv;                                                            \
            wv.x = pk2(p0, p1);                                                  \
            wv.y = pk2(p2, p3);                                                  \
            *(uint2*)((char*)pw + ((QF) * 16 + l15) * 80 + ((KT) * 16 + 4 * g) * 2) = wv; \
        }
        DOFRAG(s00, 0, 0)
        DOFRAG(s01, 1, 0)
        DOFRAG(s02, 2, 0)
        DOFRAG(s03, 3, 0)
        DOFRAG(s10, 0, 1)
        DOFRAG(s11, 1, 1)
        DOFRAG(s12, 2, 1)
        DOFRAG(s13, 3, 1)
#undef DOFRAG
        v8s pa0 = *(v8s*)((char*)pw + l15 * 80 + 16 * g);
        v8s pa1 = *(v8s*)((char*)pw + (16 + l15) * 80 + 16 * g);
        v8s pa2 = *(v8s*)((char*)pw + (32 + l15) * 80 + 16 * g);
        v8s pa3 = *(v8s*)((char*)pw + (48 + l15) * 80 + 16 * g);
        const short* vpi = vp + it * 1024;
        v8s vb0 = *(const v8s*)(vpi + l15 * 32 + 8 * g);
        v8s vb1 = *(const v8s*)(vpi + (16 + l15) * 32 + 8 * g);
        __builtin_amdgcn_s_setprio(1);
        acc[0][0] = __builtin_amdgcn_mfma_f32_16x16x32_bf16(pa0, vb0, acc[0][0], 0, 0, 0);
        acc[1][0] = __builtin_amdgcn_mfma_f32_16x16x32_bf16(pa0, vb1, acc[1][0], 0, 0, 0);
        acc[0][1] = __builtin_amdgcn_mfma_f32_16x16x32_bf16(pa1, vb0, acc[0][1], 0, 0, 0);
        acc[1][1] = __builtin_amdgcn_mfma_f32_16x16x32_bf16(pa1, vb1, acc[1][1], 0, 0, 0);
        acc[0][2] = __builtin_amdgcn_mfma_f32_16x16x32_bf16(pa2, vb0, acc[0][2], 0, 0, 0);
        acc[1][2] = __builtin_amdgcn_mfma_f32_16x16x32_bf16(pa2, vb1, acc[1][2], 0, 0, 0);
        acc[0][3] = __builtin_amdgcn_mfma_f32_16x16x32_bf16(pa3, vb0, acc[0][3], 0, 0, 0);
        acc[1][3] = __builtin_amdgcn_mfma_f32_16x16x32_bf16(pa3, vb1, acc[1][3], 0, 0, 0);
        ps[0] = __builtin_amdgcn_mfma_f32_16x16x32_bf16(pa0, ones, ps[0], 0, 0, 0);
        ps[1] = __builtin_amdgcn_mfma_f32_16x16x32_bf16(pa1, ones, ps[1], 0, 0, 0);
        ps[2] = __builtin_amdgcn_mfma_f32_16x16x32_bf16(pa2, ones, ps[2], 0, 0, 0);
        ps[3] = __builtin_amdgcn_mfma_f32_16x16x32_bf16(pa3, ones, ps[3], 0, 0, 0);
        __builtin_amdgcn_s_setprio(0);
    }

    if (l15 == 0) {
#pragma unroll
        for (int qf = 0; qf < 4; ++qf)
#pragma unroll
            for (int r = 0; r < 4; ++r)
                ps_lds[w][qf * 16 + 4 * g + r] = ps[qf][r];
    }
#pragma unroll
    for (int qf = 0; qf < 4; ++qf)
#pragma unroll
        for (int r = 0; r < 4; ++r) {
            acch[w][qf * 16 + 4 * g + r][l15]      = (short)f2b(acc[0][qf][r]);
            acch[w][qf * 16 + 4 * g + r][16 + l15] = (short)f2b(acc[1][qf][r]);
        }
    __syncthreads();

    // cooperative merge: thread t -> q = t>>3 (64), d0 = (t&7)*4
    int q = tid >> 3, d0 = (tid & 7) * 4;
    float L = (float)NN;
    float a0 = 0.f, a1 = 0.f, a2 = 0.f, a3 = 0.f;
#pragma unroll
    for (int wv = 0; wv < AW; ++wv) {
        L += ps_lds[wv][q];
        const short* row = &acch[wv][q][d0];
        a0 += b2f(row[0]); a1 += b2f(row[1]); a2 += b2f(row[2]); a3 += b2f(row[3]);
    }
    const float* vs = vsum + bh * DH + d0;
    float rl = 1.f / L;
    uint2 o;
    o.x = pk2((a0 + vs[0]) * rl, (a1 + vs[1]) * rl);
    o.y = pk2((a2 + vs[2]) * rl, (a3 + vs[3]) * rl);
    int b = bh >> 3, h = bh & 7;
    *(uint2*)&aotb[((size_t)b * NN + qbase + q) * 256 + h * DH + d0] = o;
}

// ---------------- output projection MFMA GEMM, 32o x 64n/block ----------------
__global__ __launch_bounds__(64) void k_projm(const short* __restrict__ aotb,
                                              const short* __restrict__ wprojb,
                                              const float* __restrict__ bproj,
                                              float* __restrict__ out) {
    int lane = threadIdx.x, l15 = lane & 15, g = lane >> 4;
    int blk = blockIdx.x;
    int ntg = blk % 36, otg = (blk / 36) % 8, b = blk / (36 * 8);
    int n0 = ntg * 64;
    const short* ab = aotb + (size_t)b * NN * 256;

    v4f acc[2][4];
#pragma unroll
    for (int oa = 0; oa < 2; ++oa)
#pragma unroll
        for (int j = 0; j < 4; ++j) acc[oa][j] = (v4f){0.f, 0.f, 0.f, 0.f};
#pragma unroll
    for (int kk = 0; kk < 8; ++kk) {
        v8s A0 = *(const v8s*)(wprojb + (size_t)(otg * 32 + l15) * 256 + kk * 32 + 8 * g);
        v8s A1 = *(const v8s*)(wprojb + (size_t)(otg * 32 + 16 + l15) * 256 + kk * 32 + 8 * g);
#pragma unroll
        for (int j = 0; j < 4; ++j) {
            v8s B = *(const v8s*)(ab + (size_t)(n0 + j * 16 + l15) * 256 + kk * 32 + 8 * g);
            acc[0][j] = __builtin_amdgcn_mfma_f32_16x16x32_bf16(A0, B, acc[0][j], 0, 0, 0);
            acc[1][j] = __builtin_amdgcn_mfma_f32_16x16x32_bf16(A1, B, acc[1][j], 0, 0, 0);
        }
    }
#pragma unroll
    for (int oa = 0; oa < 2; ++oa) {
        v4f bias = *(const v4f*)&bproj[otg * 32 + oa * 16 + 4 * g];
#pragma unroll
        for (int j = 0; j < 4; ++j) {
#pragma unroll
            for (int r = 0; r < 4; ++r) {
                int o = otg * 32 + oa * 16 + 4 * g + r;
                out[((size_t)b * 256 + o) * NN + n0 + j * 16 + l15] = acc[oa][j][r] + bias[r];
            }
        }
    }
}

extern "C" void kernel_launch(void* const* d_in, const int* in_sizes, int n_in,
                              void* d_out, int out_size, void* d_ws, size_t ws_size,
                              hipStream_t stream) {
    const float* x     = (const float*)d_in[0];
    const float* luma  = (const float*)d_in[1];
    const float* wqkv  = (const float*)d_in[2];
    const float* bqkv  = (const float*)d_in[3];
    const float* wproj = (const float*)d_in[4];
    const float* bproj = (const float*)d_in[5];
    const float* wc1   = (const float*)d_in[6];
    const float* bc1   = (const float*)d_in[7];
    const float* wc2   = (const float*)d_in[8];
    const float* bc2   = (const float*)d_in[9];
    const float* wg    = (const float*)d_in[10];
    const float* bg    = (const float*)d_in[11];
    const float* wbt   = (const float*)d_in[12];
    const float* bbt   = (const float*)d_in[13];
    const float* alpha = (const float*)d_in[14];
    float* out = (float*)d_out;

    float* ws = (float*)d_ws;
    size_t off = 0;
    short* tc2b = (short*)(ws + off);  off += 9 * 128 * 128 / 2;
    short* wqkvb = (short*)(ws + off); off += 768 * 256 / 2;
    short* wgb = (short*)(ws + off);   off += 256 * 128 / 2;
    short* wbtb = (short*)(ws + off);  off += 256 * 128 / 2;
    short* wprojb = (short*)(ws + off); off += 256 * 256 / 2;
    short* h1p = (short*)(ws + off);   off += NB * 2500 * 128 / 2;
    short* xt = (short*)(ws + off);    off += NB * NN * 256 / 2;
    short* gtb = (short*)(ws + off);   off += NB * NN * 256 / 2;
    short* bttb = (short*)(ws + off);  off += NB * NN * 256 / 2;
    float* invl = ws + off;            off += NB * NN;
    short* qbb = (short*)(ws + off);   off += 16 * NN * DH / 2;
    short* kbb = (short*)(ws + off);   off += 16 * NN * DH / 2;
    short* vtb = (short*)(ws + off);   off += 16 * NN * DH / 2;   // blocked [bh][72][32][32]
    float* vsum = ws + off;            off += 16 * DH;
    short* aotb = (short*)(ws + off);  off += NB * NN * 256 / 2;
    (void)ws_size; (void)in_sizes; (void)n_in; (void)out_size;

    int front_grid = NB * 144 + NB + NB * 1250 + 768;
    k_front<<<front_grid, 256, 0, stream>>>(x, xt, luma, invl, wc1, bc1, h1p,
                                            wc2, wqkv, wg, wbt, wproj,
                                            tc2b, wqkvb, wgb, wbtb, wprojb, vsum);
    k_cgb<<<NB * 144, 256, 0, stream>>>(h1p, tc2b, bc2, wgb, wbtb, bg, bbt, gtb, bttb);
    k_qkvm<<<NB * 24 * 36, 64, 0, stream>>>(xt, wqkvb, bqkv, gtb, bttb, invl, alpha,
                                            qbb, kbb, vtb, vsum);
    k_attn2<<<576, 512, 0, stream>>>(qbb, kbb, vtb, vsum, aotb);
    k_projm<<<NB * 8 * 36, 64, 0, stream>>>(aotb, wprojb, bproj, out);
}

// Round 13
// 96.110 us; speedup vs baseline: 1.1044x; 1.1044x over previous
//
#include <hip/hip_runtime.h>
#include <hip/hip_bf16.h>
#include <math.h>
#include <string.h>

#define NB 2
#define NN 2304        // 48*48
#define NHEADS 8
#define DH 32
#define AW 8           // waves per attn block
#define KPW 288        // keys per wave (NN/8)

typedef __attribute__((ext_vector_type(8))) short v8s;   // 8 bf16 in 4 VGPRs
typedef __attribute__((ext_vector_type(4))) float v4f;

__device__ inline unsigned short f2b(float f) {          // fp32 -> bf16 (RNE)
    unsigned u = __builtin_bit_cast(unsigned, f);
    unsigned r = u + 0x7FFFu + ((u >> 16) & 1u);
    return (unsigned short)(r >> 16);
}
__device__ inline float b2f(short s) {
    unsigned u = ((unsigned)(unsigned short)s) << 16;
    return __builtin_bit_cast(float, u);
}
__device__ inline unsigned pk2(float a, float b) {       // 2 fp32 -> packed bf16x2
    __hip_bfloat162 h = __float22bfloat162_rn(make_float2(a, b));
    unsigned r;
    memcpy(&r, &h, sizeof(r));
    return r;
}
__device__ inline float blo(unsigned u) { return __builtin_bit_cast(float, u << 16); }
__device__ inline float bhi(unsigned u) { return __builtin_bit_cast(float, u & 0xffff0000u); }

// ---------------- fused front: x transpose | invL | conv1 | weight prep ----------------
__global__ void k_front(const float* __restrict__ x, short* __restrict__ xt,
                        const float* __restrict__ luma, float* __restrict__ invl,
                        const float* __restrict__ wc1, const float* __restrict__ bc1,
                        short* __restrict__ h1p,
                        const float* __restrict__ wc2, const float* __restrict__ wqkv,
                        const float* __restrict__ wg, const float* __restrict__ wbt,
                        const float* __restrict__ wproj,
                        short* __restrict__ tc2b, short* __restrict__ wqkvb,
                        short* __restrict__ wgb, short* __restrict__ wbtb,
                        short* __restrict__ wprojb, float* __restrict__ vsum) {
    __shared__ unsigned short lds[64 * 66];
    __shared__ float red[256];
    int blk = blockIdx.x;
    const int XT_END = NB * 144;
    const int INVL_END = XT_END + NB;
    const int CONV1_END = INVL_END + NB * 1250;
    if (blk >= CONV1_END) {
        int i = (blk - CONV1_END) * 256 + threadIdx.x;
        if (i < 16 * DH) vsum[i] = 0.f;
        if (i < 9 * 128 * 128) {                       // tc2b[s][o][ic] = wc2[o][ic][s]
            int s = i / (128 * 128);
            int rem = i % (128 * 128);
            int o = rem / 128, ic = rem % 128;
            tc2b[i] = (short)f2b(wc2[(o * 128 + ic) * 9 + s]);
        }
        if (i < 768 * 256) wqkvb[i] = (short)f2b(wqkv[i]);
        if (i < 256 * 128) { wgb[i] = (short)f2b(wg[i]); wbtb[i] = (short)f2b(wbt[i]); }
        if (i < 256 * 256) wprojb[i] = (short)f2b(wproj[i]);
        return;
    }
    if (blk >= INVL_END) {
        // ---- conv1 -> h1p padded(50x50) transposed [b][p][128] bf16 ----
        int cb = blk - INVL_END;
        int c = threadIdx.x & 127;
        int p = (cb % 1250) * 2 + (threadIdx.x >> 7);
        int b = cb / 1250;
        int py = p / 50, px = p % 50;
        float val = 0.f;
        if (py >= 1 && py <= 48 && px >= 1 && px <= 48) {
            int y = py - 1, xx0 = px - 1;
            const float* lb = luma + b * NN;
            float acc = bc1[c];
#pragma unroll
            for (int ky = 0; ky < 3; ++ky) {
                int yy = y + ky - 1;
                if (yy < 0 || yy >= 48) continue;
#pragma unroll
                for (int kx = 0; kx < 3; ++kx) {
                    int xx = xx0 + kx - 1;
                    if (xx < 0 || xx >= 48) continue;
                    acc += wc1[c * 9 + ky * 3 + kx] * lb[yy * 48 + xx];
                }
            }
            val = fmaxf(acc, 0.f);
        }
        h1p[((size_t)b * 2500 + p) * 128 + c] = (short)f2b(val);
        return;
    }
    if (blk >= XT_END) {
        // ---- invL: avgpool3x3(1-luma) centered per batch ----
        int b = blk - XT_END;
        const float* lb = luma + b * NN;
        float pooled[9];
        float local = 0.f;
#pragma unroll
        for (int it = 0; it < 9; ++it) {
            int n = it * 256 + threadIdx.x;
            int y = n / 48, xx0 = n % 48;
            float s = 0.f;
            for (int ky = 0; ky < 3; ++ky) {
                int yy = y + ky - 1;
                if (yy < 0 || yy >= 48) continue;
                for (int kx = 0; kx < 3; ++kx) {
                    int xx = xx0 + kx - 1;
                    if (xx < 0 || xx >= 48) continue;
                    s += 1.f - lb[yy * 48 + xx];
                }
            }
            s *= (1.f / 9.f);
            pooled[it] = s;
            local += s;
        }
        red[threadIdx.x] = local;
        __syncthreads();
        for (int off = 128; off > 0; off >>= 1) {
            if (threadIdx.x < off) red[threadIdx.x] += red[threadIdx.x + off];
            __syncthreads();
        }
        float mean = red[0] * (1.f / NN);
#pragma unroll
        for (int it = 0; it < 9; ++it) {
            int n = it * 256 + threadIdx.x;
            invl[b * NN + n] = pooled[it] - mean;
        }
        return;
    }
    // ---- x transpose: [b][256][2304] fp32 -> xt [b][2304][256] bf16 ----
    int nt = blk % 36, ct = (blk / 36) % 4, b = blk / 144;
    int n0 = nt * 64, c0 = ct * 64;
    int nc = threadIdx.x & 63, cr = threadIdx.x >> 6;
#pragma unroll
    for (int i = 0; i < 16; ++i) {
        int cs = i * 4 + cr;
        float v = x[((size_t)b * 256 + c0 + cs) * NN + n0 + nc];
        lds[nc * 66 + cs] = f2b(v);
    }
    __syncthreads();
    int cc = threadIdx.x & 31, nr = threadIdx.x >> 5;
    unsigned* xt2 = (unsigned*)xt;
#pragma unroll
    for (int j = 0; j < 8; ++j) {
        int ns = j * 8 + nr;
        unsigned w = *(unsigned*)&lds[ns * 66 + 2 * cc];
        xt2[(((size_t)b * NN + n0 + ns) * 256 + c0) / 2 + cc] = w;
    }
}

// ---------------- conv2 as 9-shift MFMA GEMM, 4 n-tiles/block ----------------
__global__ __launch_bounds__(64) void k_conv2m(const short* __restrict__ h1p,
                                               const short* __restrict__ tc2b,
                                               const float* __restrict__ bc2,
                                               short* __restrict__ h2t) {
    int lane = threadIdx.x, l15 = lane & 15, g = lane >> 4;
    int blk = blockIdx.x;
    int ntg = blk % 36, ot = (blk / 36) % 8, b = blk / (36 * 8);
    int p0[4], na[4];
#pragma unroll
    for (int j = 0; j < 4; ++j) {
        int nt = ntg * 4 + j;
        int y = nt / 3, xx = (nt % 3) * 16;
        p0[j] = (y + 1) * 50 + xx + 1;
        na[j] = y * 48 + xx + l15;
    }
    const short* hb = h1p + (size_t)b * 2500 * 128;

    v4f acc[4] = {{0.f,0.f,0.f,0.f},{0.f,0.f,0.f,0.f},{0.f,0.f,0.f,0.f},{0.f,0.f,0.f,0.f}};
#pragma unroll
    for (int s = 0; s < 9; ++s) {
        int dp = (s / 3 - 1) * 50 + (s % 3 - 1);
#pragma unroll
        for (int kk = 0; kk < 4; ++kk) {
            v8s A = *(const v8s*)(tc2b + ((size_t)(s * 128 + ot * 16 + l15)) * 128 + kk * 32 + 8 * g);
#pragma unroll
            for (int j = 0; j < 4; ++j) {
                v8s B = *(const v8s*)(hb + (size_t)(p0[j] + dp + l15) * 128 + kk * 32 + 8 * g);
                acc[j] = __builtin_amdgcn_mfma_f32_16x16x32_bf16(A, B, acc[j], 0, 0, 0);
            }
        }
    }
    v4f bias = *(const v4f*)&bc2[ot * 16 + 4 * g];
#pragma unroll
    for (int j = 0; j < 4; ++j) {
        uint2 w;
        w.x = pk2(fmaxf(acc[j][0] + bias[0], 0.f), fmaxf(acc[j][1] + bias[1], 0.f));
        w.y = pk2(fmaxf(acc[j][2] + bias[2], 0.f), fmaxf(acc[j][3] + bias[3], 0.f));
        *(uint2*)&h2t[((size_t)b * NN + na[j]) * 128 + ot * 16 + 4 * g] = w;
    }
}

// ---------------- gamma/beta MFMA GEMMs, 64 n/block -> gtb/bttb bf16 [b][n][256] ----------------
__global__ __launch_bounds__(64) void k_gbm(const short* __restrict__ h2t,
                                            const short* __restrict__ wgb,
                                            const short* __restrict__ wbtb,
                                            const float* __restrict__ bg,
                                            const float* __restrict__ bbt,
                                            short* __restrict__ gtb, short* __restrict__ bttb) {
    int lane = threadIdx.x, l15 = lane & 15, g = lane >> 4;
    int blk = blockIdx.x;
    int ntg = blk % 36, ot = (blk / 36) % 16, b = blk / (36 * 16);
    int n0 = ntg * 64;
    const short* hb = h2t + (size_t)b * NN * 128;

    v4f ga[4] = {{0.f,0.f,0.f,0.f},{0.f,0.f,0.f,0.f},{0.f,0.f,0.f,0.f},{0.f,0.f,0.f,0.f}};
    v4f ta[4] = {{0.f,0.f,0.f,0.f},{0.f,0.f,0.f,0.f},{0.f,0.f,0.f,0.f},{0.f,0.f,0.f,0.f}};
#pragma unroll
    for (int kk = 0; kk < 4; ++kk) {
        v8s Ag = *(const v8s*)(wgb + (size_t)(ot * 16 + l15) * 128 + kk * 32 + 8 * g);
        v8s At = *(const v8s*)(wbtb + (size_t)(ot * 16 + l15) * 128 + kk * 32 + 8 * g);
#pragma unroll
        for (int j = 0; j < 4; ++j) {
            v8s B = *(const v8s*)(hb + (size_t)(n0 + j * 16 + l15) * 128 + kk * 32 + 8 * g);
            ga[j] = __builtin_amdgcn_mfma_f32_16x16x32_bf16(Ag, B, ga[j], 0, 0, 0);
            ta[j] = __builtin_amdgcn_mfma_f32_16x16x32_bf16(At, B, ta[j], 0, 0, 0);
        }
    }
    v4f bgv = *(const v4f*)&bg[ot * 16 + 4 * g];
    v4f bbv = *(const v4f*)&bbt[ot * 16 + 4 * g];
#pragma unroll
    for (int j = 0; j < 4; ++j) {
        size_t o = ((size_t)b * NN + n0 + j * 16 + l15) * 256 + ot * 16 + 4 * g;
        uint2 w;
        w.x = pk2(ga[j][0] + bgv[0], ga[j][1] + bgv[1]);
        w.y = pk2(ga[j][2] + bgv[2], ga[j][3] + bgv[3]);
        *(uint2*)&gtb[o] = w;
        w.x = pk2(ta[j][0] + bbv[0], ta[j][1] + bbv[1]);
        w.y = pk2(ta[j][2] + bbv[2], ta[j][3] + bbv[3]);
        *(uint2*)&bttb[o] = w;
    }
}

// ---------------- qkv MFMA GEMM, 32oc x 64n/block + modulation + fused V transpose ----------------
// which==2 (V) blocks cover one head's full d=0..31 x 64 n -> write blocked vtb directly + vsum.
__global__ __launch_bounds__(64) void k_qkvm(const short* __restrict__ xt,
                                             const short* __restrict__ wqkvb,
                                             const float* __restrict__ bqkv,
                                             const short* __restrict__ gtb,
                                             const short* __restrict__ bttb,
                                             const float* __restrict__ invl,
                                             const float* __restrict__ alpha_p,
                                             short* __restrict__ qb, short* __restrict__ kb,
                                             short* __restrict__ vtb, float* __restrict__ vsum) {
    __shared__ unsigned short vlds[64][36];   // V tile [n_local][d], 72B rows
    int lane = threadIdx.x, l15 = lane & 15, g = lane >> 4;
    int blk = blockIdx.x;
    int ntg = blk % 36, otg = (blk / 36) % 24, b = blk / (36 * 24);
    int n0 = ntg * 64;
    const short* xb = xt + (size_t)b * NN * 256;

    v4f acc[2][4];
#pragma unroll
    for (int oa = 0; oa < 2; ++oa)
#pragma unroll
        for (int j = 0; j < 4; ++j) acc[oa][j] = (v4f){0.f, 0.f, 0.f, 0.f};
#pragma unroll
    for (int kk = 0; kk < 8; ++kk) {
        v8s A0 = *(const v8s*)(wqkvb + (size_t)(otg * 32 + l15) * 256 + kk * 32 + 8 * g);
        v8s A1 = *(const v8s*)(wqkvb + (size_t)(otg * 32 + 16 + l15) * 256 + kk * 32 + 8 * g);
#pragma unroll
        for (int j = 0; j < 4; ++j) {
            v8s B = *(const v8s*)(xb + (size_t)(n0 + j * 16 + l15) * 256 + kk * 32 + 8 * g);
            acc[0][j] = __builtin_amdgcn_mfma_f32_16x16x32_bf16(A0, B, acc[0][j], 0, 0, 0);
            acc[1][j] = __builtin_amdgcn_mfma_f32_16x16x32_bf16(A1, B, acc[1][j], 0, 0, 0);
        }
    }
    const float scale = 0.25503486f;     // 32^-0.5 * log2(e)
    float alpha = *alpha_p;
    int which = (otg * 32) >> 8;
#pragma unroll
    for (int oa = 0; oa < 2; ++oa) {
        int ocb = otg * 32 + oa * 16;
        int cbase = (ocb & 255) + 4 * g;
        int h = cbase >> 5, dbase = cbase & 31;
        v4f bias = *(const v4f*)&bqkv[ocb + 4 * g];
        short* dst = (which == 0) ? qb : kb;
#pragma unroll
        for (int j = 0; j < 4; ++j) {
            int n = n0 + j * 16 + l15;
            v4f a = acc[oa][j];
            uint2 gg = *(const uint2*)&gtb[((size_t)b * NN + n) * 256 + cbase];
            uint2 tt = *(const uint2*)&bttb[((size_t)b * NN + n) * 256 + cbase];
            float iv = (which == 0) ? alpha * invl[b * NN + n] : 0.f;
            float v0 = blo(gg.x) * (a[0] + bias[0]) + blo(tt.x);
            float v1 = bhi(gg.x) * (a[1] + bias[1]) + bhi(tt.x);
            float v2 = blo(gg.y) * (a[2] + bias[2]) + blo(tt.y);
            float v3 = bhi(gg.y) * (a[3] + bias[3]) + bhi(tt.y);
            if (which == 0) {
                v0 = (v0 + iv) * scale; v1 = (v1 + iv) * scale;
                v2 = (v2 + iv) * scale; v3 = (v3 + iv) * scale;
            }
            uint2 wv;
            wv.x = pk2(v0, v1);
            wv.y = pk2(v2, v3);
            if (which == 2) {
                *(uint2*)&vlds[j * 16 + l15][oa * 16 + 4 * g] = wv;   // d = oa*16+4g..+3
            } else {
                *(uint2*)&dst[(((size_t)b * NHEADS + h) * NN + n) * DH + dbase] = wv;
            }
        }
    }
    if (which == 2) {
        __syncthreads();
        int bh = b * NHEADS + (otg - 16);
        int kb0 = ntg * 2;
        int kp = lane & 31, dh = lane >> 5;
        unsigned* vtb2 = (unsigned*)vtb;
#pragma unroll
        for (int dd = 0; dd < 16; ++dd) {
            int d = dh * 16 + dd;
            unsigned lo = vlds[2 * kp][d];
            unsigned hi = vlds[2 * kp + 1][d];
            vtb2[(((size_t)bh * 72 + kb0 + (kp >> 4)) * 32 + d) * 16 + (kp & 15)] = lo | (hi << 16);
        }
        if (lane < 32) {
            int d = lane;
            float s = 0.f;
            for (int ns = 0; ns < 64; ++ns) s += b2f((short)vlds[ns][d]);
            atomicAdd(&vsum[bh * DH + d], s);
        }
    }
}

// ---------------- fused attention: QBLK=64/wave, 8 waves split K in-block, bf16 LDS merge ----------------
__global__ __launch_bounds__(512) void k_attn2(const short* __restrict__ qb,
                                               const short* __restrict__ kbuf,
                                               const short* __restrict__ vtb,
                                               const float* __restrict__ vsum,
                                               short* __restrict__ aotb) {
    __shared__ short plds[AW][64 * 40];     // per-wave P' tile, 64 rows x 80 B
    __shared__ short acch[AW][64][36];      // per-wave partial O (bf16), 72B rows
    __shared__ float ps_lds[AW][64];        // per-wave row-sums of p'
    int tid = threadIdx.x;
    int w = tid >> 6, lane = tid & 63;
    int l15 = lane & 15, g = lane >> 4;
    int blk = blockIdx.x;
    int logical = (blk & 7) * 72 + (blk >> 3);   // XCD swizzle: 576 = 8*72
    int qt = logical % 36, bh = logical / 36;
    int qbase = qt * 64;

    const short* qp = qb + ((size_t)bh * NN + qbase) * DH;
    const short* kp = kbuf + ((size_t)bh * NN + w * KPW) * DH;
    const short* vp = vtb + ((size_t)bh * 72 + w * (KPW / 32)) * 1024;  // 32x32 tiles

    v8s q0 = *(const v8s*)(qp + l15 * DH + 8 * g);
    v8s q1 = *(const v8s*)(qp + (16 + l15) * DH + 8 * g);
    v8s q2 = *(const v8s*)(qp + (32 + l15) * DH + 8 * g);
    v8s q3 = *(const v8s*)(qp + (48 + l15) * DH + 8 * g);

    const short one_b = (short)0x3F80;      // bf16 1.0
    const v8s ones = {one_b, one_b, one_b, one_b, one_b, one_b, one_b, one_b};

    v4f acc[2][4];                          // [d-tile][q-frag]
#pragma unroll
    for (int dt = 0; dt < 2; ++dt)
#pragma unroll
        for (int qf = 0; qf < 4; ++qf) acc[dt][qf] = (v4f){0.f, 0.f, 0.f, 0.f};
    v4f ps[4] = {{0.f,0.f,0.f,0.f},{0.f,0.f,0.f,0.f},{0.f,0.f,0.f,0.f},{0.f,0.f,0.f,0.f}};
    short* pw = plds[w];

    for (int it = 0; it < KPW / 32; ++it) {
        const short* kpi = kp + it * 32 * DH;
        v8s ka0 = *(const v8s*)(kpi + l15 * DH + 8 * g);
        v8s ka1 = *(const v8s*)(kpi + (16 + l15) * DH + 8 * g);
        v4f s00 = __builtin_amdgcn_mfma_f32_16x16x32_bf16(ka0, q0, (v4f){0.f,0.f,0.f,0.f}, 0, 0, 0);
        v4f s01 = __builtin_amdgcn_mfma_f32_16x16x32_bf16(ka0, q1, (v4f){0.f,0.f,0.f,0.f}, 0, 0, 0);
        v4f s02 = __builtin_amdgcn_mfma_f32_16x16x32_bf16(ka0, q2, (v4f){0.f,0.f,0.f,0.f}, 0, 0, 0);
        v4f s03 = __builtin_amdgcn_mfma_f32_16x16x32_bf16(ka0, q3, (v4f){0.f,0.f,0.f,0.f}, 0, 0, 0);
        v4f s10 = __builtin_amdgcn_mfma_f32_16x16x32_bf16(ka1, q0, (v4f){0.f,0.f,0.f,0.f}, 0, 0, 0);
        v4f s11 = __builtin_amdgcn_mfma_f32_16x16x32_bf16(ka1, q1, (v4f){0.f,0.f,0.f,0.f}, 0, 0, 0);
        v4f s12 = __builtin_amdgcn_mfma_f32_16x16x32_bf16(ka1, q2, (v4f){0.f,0.f,0.f,0.f}, 0, 0, 0);
        v4f s13 = __builtin_amdgcn_mfma_f32_16x16x32_bf16(ka1, q3, (v4f){0.f,0.f,0.f,0.f}, 0, 0, 0);

#define DOFRAG(S, QF, KT)                                                        \
        {                                                                        \
            float p0 = __builtin_amdgcn_exp2f((S)[0]) - 1.f;                     \
            float p1 = __builtin_amdgcn_exp2f((S)[1]) - 1.f;                     \
            float p2 = __builtin_amdgcn_exp2f((S)[2]) - 1.f;                     \
            float p3 = __builtin_amdgcn_exp2f((S)[3]) - 1.f;                     \
            uint2 wv;                                                            \
            wv.x = pk2(p0, p1);                                                  \
            wv.y = pk2(p2, p3);                                                  \
            *(uint2*)((char*)pw + ((QF) * 16 + l15) * 80 + ((KT) * 16 + 4 * g) * 2) = wv; \
        }
        DOFRAG(s00, 0, 0)
        DOFRAG(s01, 1, 0)
        DOFRAG(s02, 2, 0)
        DOFRAG(s03, 3, 0)
        DOFRAG(s10, 0, 1)
        DOFRAG(s11, 1, 1)
        DOFRAG(s12, 2, 1)
        DOFRAG(s13, 3, 1)
#undef DOFRAG
        v8s pa0 = *(v8s*)((char*)pw + l15 * 80 + 16 * g);
        v8s pa1 = *(v8s*)((char*)pw + (16 + l15) * 80 + 16 * g);
        v8s pa2 = *(v8s*)((char*)pw + (32 + l15) * 80 + 16 * g);
        v8s pa3 = *(v8s*)((char*)pw + (48 + l15) * 80 + 16 * g);
        const short* vpi = vp + it * 1024;
        v8s vb0 = *(const v8s*)(vpi + l15 * 32 + 8 * g);
        v8s vb1 = *(const v8s*)(vpi + (16 + l15) * 32 + 8 * g);
        __builtin_amdgcn_s_setprio(1);
        acc[0][0] = __builtin_amdgcn_mfma_f32_16x16x32_bf16(pa0, vb0, acc[0][0], 0, 0, 0);
        acc[1][0] = __builtin_amdgcn_mfma_f32_16x16x32_bf16(pa0, vb1, acc[1][0], 0, 0, 0);
        acc[0][1] = __builtin_amdgcn_mfma_f32_16x16x32_bf16(pa1, vb0, acc[0][1], 0, 0, 0);
        acc[1][1] = __builtin_amdgcn_mfma_f32_16x16x32_bf16(pa1, vb1, acc[1][1], 0, 0, 0);
        acc[0][2] = __builtin_amdgcn_mfma_f32_16x16x32_bf16(pa2, vb0, acc[0][2], 0, 0, 0);
        acc[1][2] = __builtin_amdgcn_mfma_f32_16x16x32_bf16(pa2, vb1, acc[1][2], 0, 0, 0);
        acc[0][3] = __builtin_amdgcn_mfma_f32_16x16x32_bf16(pa3, vb0, acc[0][3], 0, 0, 0);
        acc[1][3] = __builtin_amdgcn_mfma_f32_16x16x32_bf16(pa3, vb1, acc[1][3], 0, 0, 0);
        ps[0] = __builtin_amdgcn_mfma_f32_16x16x32_bf16(pa0, ones, ps[0], 0, 0, 0);
        ps[1] = __builtin_amdgcn_mfma_f32_16x16x32_bf16(pa1, ones, ps[1], 0, 0, 0);
        ps[2] = __builtin_amdgcn_mfma_f32_16x16x32_bf16(pa2, ones, ps[2], 0, 0, 0);
        ps[3] = __builtin_amdgcn_mfma_f32_16x16x32_bf16(pa3, ones, ps[3], 0, 0, 0);
        __builtin_amdgcn_s_setprio(0);
    }

    if (l15 == 0) {
#pragma unroll
        for (int qf = 0; qf < 4; ++qf)
#pragma unroll
            for (int r = 0; r < 4; ++r)
                ps_lds[w][qf * 16 + 4 * g + r] = ps[qf][r];
    }
#pragma unroll
    for (int qf = 0; qf < 4; ++qf)
#pragma unroll
        for (int r = 0; r < 4; ++r) {
            acch[w][qf * 16 + 4 * g + r][l15]      = (short)f2b(acc[0][qf][r]);
            acch[w][qf * 16 + 4 * g + r][16 + l15] = (short)f2b(acc[1][qf][r]);
        }
    __syncthreads();

    // cooperative merge: thread t -> q = t>>3 (64), d0 = (t&7)*4
    int q = tid >> 3, d0 = (tid & 7) * 4;
    float L = (float)NN;
    float a0 = 0.f, a1 = 0.f, a2 = 0.f, a3 = 0.f;
#pragma unroll
    for (int wv = 0; wv < AW; ++wv) {
        L += ps_lds[wv][q];
        const short* row = &acch[wv][q][d0];
        a0 += b2f(row[0]); a1 += b2f(row[1]); a2 += b2f(row[2]); a3 += b2f(row[3]);
    }
    const float* vs = vsum + bh * DH + d0;
    float rl = 1.f / L;
    uint2 o;
    o.x = pk2((a0 + vs[0]) * rl, (a1 + vs[1]) * rl);
    o.y = pk2((a2 + vs[2]) * rl, (a3 + vs[3]) * rl);
    int b = bh >> 3, h = bh & 7;
    *(uint2*)&aotb[((size_t)b * NN + qbase + q) * 256 + h * DH + d0] = o;
}

// ---------------- output projection MFMA GEMM, 32o x 64n/block ----------------
__global__ __launch_bounds__(64) void k_projm(const short* __restrict__ aotb,
                                              const short* __restrict__ wprojb,
                                              const float* __restrict__ bproj,
                                              float* __restrict__ out) {
    int lane = threadIdx.x, l15 = lane & 15, g = lane >> 4;
    int blk = blockIdx.x;
    int ntg = blk % 36, otg = (blk / 36) % 8, b = blk / (36 * 8);
    int n0 = ntg * 64;
    const short* ab = aotb + (size_t)b * NN * 256;

    v4f acc[2][4];
#pragma unroll
    for (int oa = 0; oa < 2; ++oa)
#pragma unroll
        for (int j = 0; j < 4; ++j) acc[oa][j] = (v4f){0.f, 0.f, 0.f, 0.f};
#pragma unroll
    for (int kk = 0; kk < 8; ++kk) {
        v8s A0 = *(const v8s*)(wprojb + (size_t)(otg * 32 + l15) * 256 + kk * 32 + 8 * g);
        v8s A1 = *(const v8s*)(wprojb + (size_t)(otg * 32 + 16 + l15) * 256 + kk * 32 + 8 * g);
#pragma unroll
        for (int j = 0; j < 4; ++j) {
            v8s B = *(const v8s*)(ab + (size_t)(n0 + j * 16 + l15) * 256 + kk * 32 + 8 * g);
            acc[0][j] = __builtin_amdgcn_mfma_f32_16x16x32_bf16(A0, B, acc[0][j], 0, 0, 0);
            acc[1][j] = __builtin_amdgcn_mfma_f32_16x16x32_bf16(A1, B, acc[1][j], 0, 0, 0);
        }
    }
#pragma unroll
    for (int oa = 0; oa < 2; ++oa) {
        v4f bias = *(const v4f*)&bproj[otg * 32 + oa * 16 + 4 * g];
#pragma unroll
        for (int j = 0; j < 4; ++j) {
#pragma unroll
            for (int r = 0; r < 4; ++r) {
                int o = otg * 32 + oa * 16 + 4 * g + r;
                out[((size_t)b * 256 + o) * NN + n0 + j * 16 + l15] = acc[oa][j][r] + bias[r];
            }
        }
    }
}

extern "C" void kernel_launch(void* const* d_in, const int* in_sizes, int n_in,
                              void* d_out, int out_size, void* d_ws, size_t ws_size,
                              hipStream_t stream) {
    const float* x     = (const float*)d_in[0];
    const float* luma  = (const float*)d_in[1];
    const float* wqkv  = (const float*)d_in[2];
    const float* bqkv  = (const float*)d_in[3];
    const float* wproj = (const float*)d_in[4];
    const float* bproj = (const float*)d_in[5];
    const float* wc1   = (const float*)d_in[6];
    const float* bc1   = (const float*)d_in[7];
    const float* wc2   = (const float*)d_in[8];
    const float* bc2   = (const float*)d_in[9];
    const float* wg    = (const float*)d_in[10];
    const float* bg    = (const float*)d_in[11];
    const float* wbt   = (const float*)d_in[12];
    const float* bbt   = (const float*)d_in[13];
    const float* alpha = (const float*)d_in[14];
    float* out = (float*)d_out;

    float* ws = (float*)d_ws;
    size_t off = 0;
    short* tc2b = (short*)(ws + off);  off += 9 * 128 * 128 / 2;
    short* wqkvb = (short*)(ws + off); off += 768 * 256 / 2;
    short* wgb = (short*)(ws + off);   off += 256 * 128 / 2;
    short* wbtb = (short*)(ws + off);  off += 256 * 128 / 2;
    short* wprojb = (short*)(ws + off); off += 256 * 256 / 2;
    short* h1p = (short*)(ws + off);   off += NB * 2500 * 128 / 2;
    short* xt = (short*)(ws + off);    off += NB * NN * 256 / 2;
    short* h2t = (short*)(ws + off);   off += NB * NN * 128 / 2;
    short* gtb = (short*)(ws + off);   off += NB * NN * 256 / 2;
    short* bttb = (short*)(ws + off);  off += NB * NN * 256 / 2;
    float* invl = ws + off;            off += NB * NN;
    short* qbb = (short*)(ws + off);   off += 16 * NN * DH / 2;
    short* kbb = (short*)(ws + off);   off += 16 * NN * DH / 2;
    short* vtb = (short*)(ws + off);   off += 16 * NN * DH / 2;   // blocked [bh][72][32][32]
    float* vsum = ws + off;            off += 16 * DH;
    short* aotb = (short*)(ws + off);  off += NB * NN * 256 / 2;
    (void)ws_size; (void)in_sizes; (void)n_in; (void)out_size;

    int front_grid = NB * 144 + NB + NB * 1250 + 768;
    k_front<<<front_grid, 256, 0, stream>>>(x, xt, luma, invl, wc1, bc1, h1p,
                                            wc2, wqkv, wg, wbt, wproj,
                                            tc2b, wqkvb, wgb, wbtb, wprojb, vsum);
    k_conv2m<<<NB * 8 * 36, 64, 0, stream>>>(h1p, tc2b, bc2, h2t);
    k_gbm<<<NB * 16 * 36, 64, 0, stream>>>(h2t, wgb, wbtb, bg, bbt, gtb, bttb);
    k_qkvm<<<NB * 24 * 36, 64, 0, stream>>>(xt, wqkvb, bqkv, gtb, bttb, invl, alpha,
                                            qbb, kbb, vtb, vsum);
    k_attn2<<<576, 512, 0, stream>>>(qbb, kbb, vtb, vsum, aotb);
    k_projm<<<NB * 8 * 36, 64, 0, stream>>>(aotb, wprojb, bproj, out);
}

// Round 14
// 91.576 us; speedup vs baseline: 1.1591x; 1.0495x over previous
//
#include <hip/hip_runtime.h>
#include <hip/hip_bf16.h>
#include <math.h>
#include <string.h>

#define NB 2
#define NN 2304        // 48*48
#define NHEADS 8
#define DH 32
#define AW 8           // waves per attn block
#define KPW 288        // keys per wave (NN/8)

typedef __attribute__((ext_vector_type(8))) short v8s;   // 8 bf16 in 4 VGPRs
typedef __attribute__((ext_vector_type(4))) float v4f;
typedef __attribute__((ext_vector_type(16))) float v16f;

__device__ inline unsigned short f2b(float f) {          // fp32 -> bf16 (RNE)
    unsigned u = __builtin_bit_cast(unsigned, f);
    unsigned r = u + 0x7FFFu + ((u >> 16) & 1u);
    return (unsigned short)(r >> 16);
}
__device__ inline float b2f(short s) {
    unsigned u = ((unsigned)(unsigned short)s) << 16;
    return __builtin_bit_cast(float, u);
}
__device__ inline unsigned pk2(float a, float b) {       // 2 fp32 -> packed bf16x2
    __hip_bfloat162 h = __float22bfloat162_rn(make_float2(a, b));
    unsigned r;
    memcpy(&r, &h, sizeof(r));
    return r;
}
__device__ inline float blo(unsigned u) { return __builtin_bit_cast(float, u << 16); }
__device__ inline float bhi(unsigned u) { return __builtin_bit_cast(float, u & 0xffff0000u); }

// ---------------- fused front: x transpose | invL | conv1 | weight prep ----------------
__global__ void k_front(const float* __restrict__ x, short* __restrict__ xt,
                        const float* __restrict__ luma, float* __restrict__ invl,
                        const float* __restrict__ wc1, const float* __restrict__ bc1,
                        short* __restrict__ h1p,
                        const float* __restrict__ wc2, const float* __restrict__ wqkv,
                        const float* __restrict__ wg, const float* __restrict__ wbt,
                        const float* __restrict__ wproj,
                        short* __restrict__ tc2b, short* __restrict__ wqkvb,
                        short* __restrict__ wgb, short* __restrict__ wbtb,
                        short* __restrict__ wprojb, float* __restrict__ vsum) {
    __shared__ unsigned short lds[64 * 66];
    __shared__ float red[256];
    int blk = blockIdx.x;
    const int XT_END = NB * 144;
    const int INVL_END = XT_END + NB;
    const int CONV1_END = INVL_END + NB * 1250;
    if (blk >= CONV1_END) {
        int i = (blk - CONV1_END) * 256 + threadIdx.x;
        if (i < 16 * DH) vsum[i] = 0.f;
        if (i < 9 * 128 * 128) {                       // tc2b[s][o][ic] = wc2[o][ic][s]
            int s = i / (128 * 128);
            int rem = i % (128 * 128);
            int o = rem / 128, ic = rem % 128;
            tc2b[i] = (short)f2b(wc2[(o * 128 + ic) * 9 + s]);
        }
        if (i < 768 * 256) wqkvb[i] = (short)f2b(wqkv[i]);
        if (i < 256 * 128) { wgb[i] = (short)f2b(wg[i]); wbtb[i] = (short)f2b(wbt[i]); }
        if (i < 256 * 256) wprojb[i] = (short)f2b(wproj[i]);
        return;
    }
    if (blk >= INVL_END) {
        // ---- conv1 -> h1p padded(50x50) transposed [b][p][128] bf16 ----
        int cb = blk - INVL_END;
        int c = threadIdx.x & 127;
        int p = (cb % 1250) * 2 + (threadIdx.x >> 7);
        int b = cb / 1250;
        int py = p / 50, px = p % 50;
        float val = 0.f;
        if (py >= 1 && py <= 48 && px >= 1 && px <= 48) {
            int y = py - 1, xx0 = px - 1;
            const float* lb = luma + b * NN;
            float acc = bc1[c];
#pragma unroll
            for (int ky = 0; ky < 3; ++ky) {
                int yy = y + ky - 1;
                if (yy < 0 || yy >= 48) continue;
#pragma unroll
                for (int kx = 0; kx < 3; ++kx) {
                    int xx = xx0 + kx - 1;
                    if (xx < 0 || xx >= 48) continue;
                    acc += wc1[c * 9 + ky * 3 + kx] * lb[yy * 48 + xx];
                }
            }
            val = fmaxf(acc, 0.f);
        }
        h1p[((size_t)b * 2500 + p) * 128 + c] = (short)f2b(val);
        return;
    }
    if (blk >= XT_END) {
        // ---- invL: avgpool3x3(1-luma) centered per batch ----
        int b = blk - XT_END;
        const float* lb = luma + b * NN;
        float pooled[9];
        float local = 0.f;
#pragma unroll
        for (int it = 0; it < 9; ++it) {
            int n = it * 256 + threadIdx.x;
            int y = n / 48, xx0 = n % 48;
            float s = 0.f;
            for (int ky = 0; ky < 3; ++ky) {
                int yy = y + ky - 1;
                if (yy < 0 || yy >= 48) continue;
                for (int kx = 0; kx < 3; ++kx) {
                    int xx = xx0 + kx - 1;
                    if (xx < 0 || xx >= 48) continue;
                    s += 1.f - lb[yy * 48 + xx];
                }
            }
            s *= (1.f / 9.f);
            pooled[it] = s;
            local += s;
        }
        red[threadIdx.x] = local;
        __syncthreads();
        for (int off = 128; off > 0; off >>= 1) {
            if (threadIdx.x < off) red[threadIdx.x] += red[threadIdx.x + off];
            __syncthreads();
        }
        float mean = red[0] * (1.f / NN);
#pragma unroll
        for (int it = 0; it < 9; ++it) {
            int n = it * 256 + threadIdx.x;
            invl[b * NN + n] = pooled[it] - mean;
        }
        return;
    }
    // ---- x transpose: [b][256][2304] fp32 -> xt [b][2304][256] bf16 ----
    int nt = blk % 36, ct = (blk / 36) % 4, b = blk / 144;
    int n0 = nt * 64, c0 = ct * 64;
    int nc = threadIdx.x & 63, cr = threadIdx.x >> 6;
#pragma unroll
    for (int i = 0; i < 16; ++i) {
        int cs = i * 4 + cr;
        float v = x[((size_t)b * 256 + c0 + cs) * NN + n0 + nc];
        lds[nc * 66 + cs] = f2b(v);
    }
    __syncthreads();
    int cc = threadIdx.x & 31, nr = threadIdx.x >> 5;
    unsigned* xt2 = (unsigned*)xt;
#pragma unroll
    for (int j = 0; j < 8; ++j) {
        int ns = j * 8 + nr;
        unsigned w = *(unsigned*)&lds[ns * 66 + 2 * cc];
        xt2[(((size_t)b * NN + n0 + ns) * 256 + c0) / 2 + cc] = w;
    }
}

// ---------------- conv2 as 9-shift MFMA GEMM, 4 n-tiles/block ----------------
__global__ __launch_bounds__(64) void k_conv2m(const short* __restrict__ h1p,
                                               const short* __restrict__ tc2b,
                                               const float* __restrict__ bc2,
                                               short* __restrict__ h2t) {
    int lane = threadIdx.x, l15 = lane & 15, g = lane >> 4;
    int blk = blockIdx.x;
    int ntg = blk % 36, ot = (blk / 36) % 8, b = blk / (36 * 8);
    int p0[4], na[4];
#pragma unroll
    for (int j = 0; j < 4; ++j) {
        int nt = ntg * 4 + j;
        int y = nt / 3, xx = (nt % 3) * 16;
        p0[j] = (y + 1) * 50 + xx + 1;
        na[j] = y * 48 + xx + l15;
    }
    const short* hb = h1p + (size_t)b * 2500 * 128;

    v4f acc[4] = {{0.f,0.f,0.f,0.f},{0.f,0.f,0.f,0.f},{0.f,0.f,0.f,0.f},{0.f,0.f,0.f,0.f}};
#pragma unroll
    for (int s = 0; s < 9; ++s) {
        int dp = (s / 3 - 1) * 50 + (s % 3 - 1);
#pragma unroll
        for (int kk = 0; kk < 4; ++kk) {
            v8s A = *(const v8s*)(tc2b + ((size_t)(s * 128 + ot * 16 + l15)) * 128 + kk * 32 + 8 * g);
#pragma unroll
            for (int j = 0; j < 4; ++j) {
                v8s B = *(const v8s*)(hb + (size_t)(p0[j] + dp + l15) * 128 + kk * 32 + 8 * g);
                acc[j] = __builtin_amdgcn_mfma_f32_16x16x32_bf16(A, B, acc[j], 0, 0, 0);
            }
        }
    }
    v4f bias = *(const v4f*)&bc2[ot * 16 + 4 * g];
#pragma unroll
    for (int j = 0; j < 4; ++j) {
        uint2 w;
        w.x = pk2(fmaxf(acc[j][0] + bias[0], 0.f), fmaxf(acc[j][1] + bias[1], 0.f));
        w.y = pk2(fmaxf(acc[j][2] + bias[2], 0.f), fmaxf(acc[j][3] + bias[3], 0.f));
        *(uint2*)&h2t[((size_t)b * NN + na[j]) * 128 + ot * 16 + 4 * g] = w;
    }
}

// ---------------- gamma/beta MFMA GEMMs, 64 n/block -> gtb/bttb bf16 [b][n][256] ----------------
__global__ __launch_bounds__(64) void k_gbm(const short* __restrict__ h2t,
                                            const short* __restrict__ wgb,
                                            const short* __restrict__ wbtb,
                                            const float* __restrict__ bg,
                                            const float* __restrict__ bbt,
                                            short* __restrict__ gtb, short* __restrict__ bttb) {
    int lane = threadIdx.x, l15 = lane & 15, g = lane >> 4;
    int blk = blockIdx.x;
    int ntg = blk % 36, ot = (blk / 36) % 16, b = blk / (36 * 16);
    int n0 = ntg * 64;
    const short* hb = h2t + (size_t)b * NN * 128;

    v4f ga[4] = {{0.f,0.f,0.f,0.f},{0.f,0.f,0.f,0.f},{0.f,0.f,0.f,0.f},{0.f,0.f,0.f,0.f}};
    v4f ta[4] = {{0.f,0.f,0.f,0.f},{0.f,0.f,0.f,0.f},{0.f,0.f,0.f,0.f},{0.f,0.f,0.f,0.f}};
#pragma unroll
    for (int kk = 0; kk < 4; ++kk) {
        v8s Ag = *(const v8s*)(wgb + (size_t)(ot * 16 + l15) * 128 + kk * 32 + 8 * g);
        v8s At = *(const v8s*)(wbtb + (size_t)(ot * 16 + l15) * 128 + kk * 32 + 8 * g);
#pragma unroll
        for (int j = 0; j < 4; ++j) {
            v8s B = *(const v8s*)(hb + (size_t)(n0 + j * 16 + l15) * 128 + kk * 32 + 8 * g);
            ga[j] = __builtin_amdgcn_mfma_f32_16x16x32_bf16(Ag, B, ga[j], 0, 0, 0);
            ta[j] = __builtin_amdgcn_mfma_f32_16x16x32_bf16(At, B, ta[j], 0, 0, 0);
        }
    }
    v4f bgv = *(const v4f*)&bg[ot * 16 + 4 * g];
    v4f bbv = *(const v4f*)&bbt[ot * 16 + 4 * g];
#pragma unroll
    for (int j = 0; j < 4; ++j) {
        size_t o = ((size_t)b * NN + n0 + j * 16 + l15) * 256 + ot * 16 + 4 * g;
        uint2 w;
        w.x = pk2(ga[j][0] + bgv[0], ga[j][1] + bgv[1]);
        w.y = pk2(ga[j][2] + bgv[2], ga[j][3] + bgv[3]);
        *(uint2*)&gtb[o] = w;
        w.x = pk2(ta[j][0] + bbv[0], ta[j][1] + bbv[1]);
        w.y = pk2(ta[j][2] + bbv[2], ta[j][3] + bbv[3]);
        *(uint2*)&bttb[o] = w;
    }
}

// ---------------- qkv MFMA GEMM, 32oc x 64n/block + modulation + fused V transpose ----------------
__global__ __launch_bounds__(64) void k_qkvm(const short* __restrict__ xt,
                                             const short* __restrict__ wqkvb,
                                             const float* __restrict__ bqkv,
                                             const short* __restrict__ gtb,
                                             const short* __restrict__ bttb,
                                             const float* __restrict__ invl,
                                             const float* __restrict__ alpha_p,
                                             short* __restrict__ qb, short* __restrict__ kb,
                                             short* __restrict__ vtb, float* __restrict__ vsum) {
    __shared__ unsigned short vlds[64][36];   // V tile [n_local][d], 72B rows
    int lane = threadIdx.x, l15 = lane & 15, g = lane >> 4;
    int blk = blockIdx.x;
    int ntg = blk % 36, otg = (blk / 36) % 24, b = blk / (36 * 24);
    int n0 = ntg * 64;
    const short* xb = xt + (size_t)b * NN * 256;

    v4f acc[2][4];
#pragma unroll
    for (int oa = 0; oa < 2; ++oa)
#pragma unroll
        for (int j = 0; j < 4; ++j) acc[oa][j] = (v4f){0.f, 0.f, 0.f, 0.f};
#pragma unroll
    for (int kk = 0; kk < 8; ++kk) {
        v8s A0 = *(const v8s*)(wqkvb + (size_t)(otg * 32 + l15) * 256 + kk * 32 + 8 * g);
        v8s A1 = *(const v8s*)(wqkvb + (size_t)(otg * 32 + 16 + l15) * 256 + kk * 32 + 8 * g);
#pragma unroll
        for (int j = 0; j < 4; ++j) {
            v8s B = *(const v8s*)(xb + (size_t)(n0 + j * 16 + l15) * 256 + kk * 32 + 8 * g);
            acc[0][j] = __builtin_amdgcn_mfma_f32_16x16x32_bf16(A0, B, acc[0][j], 0, 0, 0);
            acc[1][j] = __builtin_amdgcn_mfma_f32_16x16x32_bf16(A1, B, acc[1][j], 0, 0, 0);
        }
    }
    const float scale = 0.25503486f;     // 32^-0.5 * log2(e)
    float alpha = *alpha_p;
    int which = (otg * 32) >> 8;
#pragma unroll
    for (int oa = 0; oa < 2; ++oa) {
        int ocb = otg * 32 + oa * 16;
        int cbase = (ocb & 255) + 4 * g;
        int h = cbase >> 5, dbase = cbase & 31;
        v4f bias = *(const v4f*)&bqkv[ocb + 4 * g];
        short* dst = (which == 0) ? qb : kb;
#pragma unroll
        for (int j = 0; j < 4; ++j) {
            int n = n0 + j * 16 + l15;
            v4f a = acc[oa][j];
            uint2 gg = *(const uint2*)&gtb[((size_t)b * NN + n) * 256 + cbase];
            uint2 tt = *(const uint2*)&bttb[((size_t)b * NN + n) * 256 + cbase];
            float iv = (which == 0) ? alpha * invl[b * NN + n] : 0.f;
            float v0 = blo(gg.x) * (a[0] + bias[0]) + blo(tt.x);
            float v1 = bhi(gg.x) * (a[1] + bias[1]) + bhi(tt.x);
            float v2 = blo(gg.y) * (a[2] + bias[2]) + blo(tt.y);
            float v3 = bhi(gg.y) * (a[3] + bias[3]) + bhi(tt.y);
            if (which == 0) {
                v0 = (v0 + iv) * scale; v1 = (v1 + iv) * scale;
                v2 = (v2 + iv) * scale; v3 = (v3 + iv) * scale;
            }
            uint2 wv;
            wv.x = pk2(v0, v1);
            wv.y = pk2(v2, v3);
            if (which == 2) {
                *(uint2*)&vlds[j * 16 + l15][oa * 16 + 4 * g] = wv;   // d = oa*16+4g..+3
            } else {
                *(uint2*)&dst[(((size_t)b * NHEADS + h) * NN + n) * DH + dbase] = wv;
            }
        }
    }
    if (which == 2) {
        __syncthreads();
        int bh = b * NHEADS + (otg - 16);
        int kb0 = ntg * 2;
        int kp = lane & 31, dh = lane >> 5;
        unsigned* vtb2 = (unsigned*)vtb;
#pragma unroll
        for (int dd = 0; dd < 16; ++dd) {
            int d = dh * 16 + dd;
            unsigned lo = vlds[2 * kp][d];
            unsigned hi = vlds[2 * kp + 1][d];
            vtb2[(((size_t)bh * 72 + kb0 + (kp >> 4)) * 32 + d) * 16 + (kp & 15)] = lo | (hi << 16);
        }
        if (lane < 32) {
            int d = lane;
            float s = 0.f;
            for (int ns = 0; ns < 64; ++ns) s += b2f((short)vlds[ns][d]);
            atomicAdd(&vsum[bh * DH + d], s);
        }
    }
}

// ---------------- fused attention: 32x32 MFMA, in-register P via permuted-K, no LDS in loop ----------------
// grid 1152 (XCD-swizzled), block 512 (8 waves, K split 8).  p' = exp2(s)-1 (s pre-scaled by log2e).
// QK^T computed as mfma32(A=K[sigma(m)], B=Q): C col=q=lane&31, row k permuted so each lane's
// 16 P' values are exactly its PV A-frag elements (k = 16*ks + 8h + j). Row-sums via MFMA ones.
__global__ __launch_bounds__(512) void k_attn2(const short* __restrict__ qb,
                                               const short* __restrict__ kbuf,
                                               const short* __restrict__ vtb,
                                               const float* __restrict__ vsum,
                                               short* __restrict__ aotb) {
    __shared__ short acch[AW][32][33];      // per-wave partial O (bf16)
    __shared__ float ps_lds[AW][32];        // per-wave row-sums of p'
    int tid = threadIdx.x;
    int w = tid >> 6, lane = tid & 63;
    int l31 = lane & 31, h = lane >> 5;
    int blk = blockIdx.x;
    int logical = (blk & 7) * 144 + (blk >> 3);   // XCD swizzle: 1152 = 8*144
    int qt = logical % 72, bh = logical / 72;
    int qbase = qt * 32;

    const short* qp = qb + ((size_t)bh * NN + qbase) * DH;
    const short* kp = kbuf + ((size_t)bh * NN + w * KPW) * DH;
    const short* vp = vtb + ((size_t)bh * 72 + w * (KPW / 32)) * 1024;  // 32x32 [d][k] tiles

    // K-row permutation: sigma(m) = 16*(m>>4) + 8*((m>>2)&1) + 4*((m>>3)&1) + (m&3)
    int m = l31;
    int sig = 16 * (m >> 4) + 8 * ((m >> 2) & 1) + 4 * ((m >> 3) & 1) + (m & 3);

    // Q B-frags: lane: q = l31, d = 16*s + 8h + j
    v8s q0 = *(const v8s*)(qp + l31 * DH + 8 * h);
    v8s q1 = *(const v8s*)(qp + l31 * DH + 16 + 8 * h);

    const short one_b = (short)0x3F80;      // bf16 1.0
    const v8s ones = {one_b, one_b, one_b, one_b, one_b, one_b, one_b, one_b};
    const v16f vz = {0.f,0.f,0.f,0.f,0.f,0.f,0.f,0.f,0.f,0.f,0.f,0.f,0.f,0.f,0.f,0.f};

    v16f accO = vz, ps = vz;

    for (int it = 0; it < KPW / 32; ++it) {
        const short* kpi = kp + it * 32 * DH;
        // K A-frags with permuted row: physical key sigma(l31), d = 16*s + 8h + j
        v8s ka0 = *(const v8s*)(kpi + sig * DH + 8 * h);
        v8s ka1 = *(const v8s*)(kpi + sig * DH + 16 + 8 * h);
        v16f sC = __builtin_amdgcn_mfma_f32_32x32x16_bf16(ka0, q0, vz, 0, 0, 0);
        sC = __builtin_amdgcn_mfma_f32_32x32x16_bf16(ka1, q1, sC, 0, 0, 0);

        // p'[r] = exp2(sC[r]) - 1; element r holds k = 16*(r>>3) + 8h + (r&7) for this lane's q=l31
        float p[16];
#pragma unroll
        for (int r = 0; r < 16; ++r) p[r] = __builtin_amdgcn_exp2f(sC[r]) - 1.f;
        unsigned w0[4], w1[4];
#pragma unroll
        for (int i = 0; i < 4; ++i) {
            w0[i] = pk2(p[2 * i], p[2 * i + 1]);          // ks=0: k = 8h + 0..7
            w1[i] = pk2(p[8 + 2 * i], p[9 + 2 * i]);      // ks=1: k = 16 + 8h + 0..7
        }
        v8s pa0, pa1;
        memcpy(&pa0, w0, 16);
        memcpy(&pa1, w1, 16);

        // V B-frags from blocked [d][k] tile: lane: d = l31, k = 16*ks + 8h + j
        const short* vpi = vp + it * 1024;
        v8s vb0 = *(const v8s*)(vpi + l31 * 32 + 8 * h);
        v8s vb1 = *(const v8s*)(vpi + l31 * 32 + 16 + 8 * h);

        __builtin_amdgcn_s_setprio(1);
        accO = __builtin_amdgcn_mfma_f32_32x32x16_bf16(pa0, vb0, accO, 0, 0, 0);
        accO = __builtin_amdgcn_mfma_f32_32x32x16_bf16(pa1, vb1, accO, 0, 0, 0);
        ps = __builtin_amdgcn_mfma_f32_32x32x16_bf16(pa0, ones, ps, 0, 0, 0);
        ps = __builtin_amdgcn_mfma_f32_32x32x16_bf16(pa1, ones, ps, 0, 0, 0);
        __builtin_amdgcn_s_setprio(0);
    }

    // dump: accO C layout: col = d = l31, row q = (r&3) + 8*(r>>2) + 4h
#pragma unroll
    for (int r = 0; r < 16; ++r) {
        int qr = (r & 3) + 8 * (r >> 2) + 4 * h;
        acch[w][qr][l31] = (short)f2b(accO[r]);
    }
    if (l31 == 0) {
#pragma unroll
        for (int r = 0; r < 16; ++r) {
            int qr = (r & 3) + 8 * (r >> 2) + 4 * h;
            ps_lds[w][qr] = ps[r];
        }
    }
    __syncthreads();

    // cooperative merge: thread t -> q = t>>4 (32), dp = t&15 -> d0 = 2*dp
    int q = tid >> 4, d0 = (tid & 15) * 2;
    float L = (float)NN;
    float a0 = 0.f, a1 = 0.f;
#pragma unroll
    for (int wv = 0; wv < AW; ++wv) {
        L += ps_lds[wv][q];
        a0 += b2f(acch[wv][q][d0]);
        a1 += b2f(acch[wv][q][d0 + 1]);
    }
    const float* vs = vsum + bh * DH + d0;
    float rl = 1.f / L;
    unsigned o = pk2((a0 + vs[0]) * rl, (a1 + vs[1]) * rl);
    int b = bh >> 3, hh = bh & 7;
    *(unsigned*)&aotb[((size_t)b * NN + qbase + q) * 256 + hh * DH + d0] = o;
}

// ---------------- output projection MFMA GEMM, 32o x 64n/block ----------------
__global__ __launch_bounds__(64) void k_projm(const short* __restrict__ aotb,
                                              const short* __restrict__ wprojb,
                                              const float* __restrict__ bproj,
                                              float* __restrict__ out) {
    int lane = threadIdx.x, l15 = lane & 15, g = lane >> 4;
    int blk = blockIdx.x;
    int ntg = blk % 36, otg = (blk / 36) % 8, b = blk / (36 * 8);
    int n0 = ntg * 64;
    const short* ab = aotb + (size_t)b * NN * 256;

    v4f acc[2][4];
#pragma unroll
    for (int oa = 0; oa < 2; ++oa)
#pragma unroll
        for (int j = 0; j < 4; ++j) acc[oa][j] = (v4f){0.f, 0.f, 0.f, 0.f};
#pragma unroll
    for (int kk = 0; kk < 8; ++kk) {
        v8s A0 = *(const v8s*)(wprojb + (size_t)(otg * 32 + l15) * 256 + kk * 32 + 8 * g);
        v8s A1 = *(const v8s*)(wprojb + (size_t)(otg * 32 + 16 + l15) * 256 + kk * 32 + 8 * g);
#pragma unroll
        for (int j = 0; j < 4; ++j) {
            v8s B = *(const v8s*)(ab + (size_t)(n0 + j * 16 + l15) * 256 + kk * 32 + 8 * g);
            acc[0][j] = __builtin_amdgcn_mfma_f32_16x16x32_bf16(A0, B, acc[0][j], 0, 0, 0);
            acc[1][j] = __builtin_amdgcn_mfma_f32_16x16x32_bf16(A1, B, acc[1][j], 0, 0, 0);
        }
    }
#pragma unroll
    for (int oa = 0; oa < 2; ++oa) {
        v4f bias = *(const v4f*)&bproj[otg * 32 + oa * 16 + 4 * g];
#pragma unroll
        for (int j = 0; j < 4; ++j) {
#pragma unroll
            for (int r = 0; r < 4; ++r) {
                int o = otg * 32 + oa * 16 + 4 * g + r;
                out[((size_t)b * 256 + o) * NN + n0 + j * 16 + l15] = acc[oa][j][r] + bias[r];
            }
        }
    }
}

extern "C" void kernel_launch(void* const* d_in, const int* in_sizes, int n_in,
                              void* d_out, int out_size, void* d_ws, size_t ws_size,
                              hipStream_t stream) {
    const float* x     = (const float*)d_in[0];
    const float* luma  = (const float*)d_in[1];
    const float* wqkv  = (const float*)d_in[2];
    const float* bqkv  = (const float*)d_in[3];
    const float* wproj = (const float*)d_in[4];
    const float* bproj = (const float*)d_in[5];
    const float* wc1   = (const float*)d_in[6];
    const float* bc1   = (const float*)d_in[7];
    const float* wc2   = (const float*)d_in[8];
    const float* bc2   = (const float*)d_in[9];
    const float* wg    = (const float*)d_in[10];
    const float* bg    = (const float*)d_in[11];
    const float* wbt   = (const float*)d_in[12];
    const float* bbt   = (const float*)d_in[13];
    const float* alpha = (const float*)d_in[14];
    float* out = (float*)d_out;

    float* ws = (float*)d_ws;
    size_t off = 0;
    short* tc2b = (short*)(ws + off);  off += 9 * 128 * 128 / 2;
    short* wqkvb = (short*)(ws + off); off += 768 * 256 / 2;
    short* wgb = (short*)(ws + off);   off += 256 * 128 / 2;
    short* wbtb = (short*)(ws + off);  off += 256 * 128 / 2;
    short* wprojb = (short*)(ws + off); off += 256 * 256 / 2;
    short* h1p = (short*)(ws + off);   off += NB * 2500 * 128 / 2;
    short* xt = (short*)(ws + off);    off += NB * NN * 256 / 2;
    short* h2t = (short*)(ws + off);   off += NB * NN * 128 / 2;
    short* gtb = (short*)(ws + off);   off += NB * NN * 256 / 2;
    short* bttb = (short*)(ws + off);  off += NB * NN * 256 / 2;
    float* invl = ws + off;            off += NB * NN;
    short* qbb = (short*)(ws + off);   off += 16 * NN * DH / 2;
    short* kbb = (short*)(ws + off);   off += 16 * NN * DH / 2;
    short* vtb = (short*)(ws + off);   off += 16 * NN * DH / 2;   // blocked [bh][72][32][32]
    float* vsum = ws + off;            off += 16 * DH;
    short* aotb = (short*)(ws + off);  off += NB * NN * 256 / 2;
    (void)ws_size; (void)in_sizes; (void)n_in; (void)out_size;

    int front_grid = NB * 144 + NB + NB * 1250 + 768;
    k_front<<<front_grid, 256, 0, stream>>>(x, xt, luma, invl, wc1, bc1, h1p,
                                            wc2, wqkv, wg, wbt, wproj,
                                            tc2b, wqkvb, wgb, wbtb, wprojb, vsum);
    k_conv2m<<<NB * 8 * 36, 64, 0, stream>>>(h1p, tc2b, bc2, h2t);
    k_gbm<<<NB * 16 * 36, 64, 0, stream>>>(h2t, wgb, wbtb, bg, bbt, gtb, bttb);
    k_qkvm<<<NB * 24 * 36, 64, 0, stream>>>(xt, wqkvb, bqkv, gtb, bttb, invl, alpha,
                                            qbb, kbb, vtb, vsum);
    k_attn2<<<1152, 512, 0, stream>>>(qbb, kbb, vtb, vsum, aotb);
    k_projm<<<NB * 8 * 36, 64, 0, stream>>>(aotb, wprojb, bproj, out);
}